// Round 12
// baseline (1010.203 us; speedup 1.0000x reference)
//
#include <hip/hip_runtime.h>
#include <hip/hip_cooperative_groups.h>
#include <hip/hip_bf16.h>
#include <stdint.h>
#include <stddef.h>

#define NEG_SLOPE 0.2f

// CSR bucket build: bucket = dst >> 9 (512 nodes/bucket), 196 buckets for N=100k.
#define NBK   196
#define BWSH  9
#define BCAP  12288
#define WTS_TOTAL 20993

typedef __bf16 bf16x8 __attribute__((ext_vector_type(8)));
typedef float  f32x4  __attribute__((ext_vector_type(4)));

__device__ __forceinline__ float bf2f(__hip_bfloat16 b){ return __bfloat162float(b); }
__device__ __forceinline__ float lo_bf(unsigned u){ return __uint_as_float(u << 16); }
__device__ __forceinline__ float hi_bf(unsigned u){ return __uint_as_float(u & 0xffff0000u); }
__device__ __forceinline__ float lrelu(float u){ return fmaxf(u, NEG_SLOPE * u); }
__device__ __forceinline__ unsigned short f2bf(float f){           // RNE bf16
    unsigned u = __float_as_uint(f);
    return (unsigned short)((u + 0x7fffu + ((u >> 16) & 1u)) >> 16);
}
__device__ __forceinline__ float bfs2f(unsigned short s){ return __uint_as_float((unsigned)s << 16); }
__device__ __forceinline__ float ldraw(const void* p, int i, int isf){
    return isf ? ((const float*)p)[i] : bf2f(((const __hip_bfloat16*)p)[i]);
}

struct GParams {
    const void* ei; const unsigned* xw;
    const void *W1, *W2, *a1s, *a1d, *b1, *a2s, *a2d, *b2, *Wh, *bh;
    float* wts; unsigned short* w1x; unsigned short* w2x;
    int* gcur; int* rowptr; int* csrs; unsigned* pairs;
    unsigned short* h1b; float* as1; float* ad1;
    unsigned* out1u; unsigned short* h2b; float* as2; float* ad2;
    void* out;
    int Nn, Ee, Et, nsb, ngemm, nq;
};

// One cooperative kernel, 6 grid-stride phases separated by grid.sync().
// Static LDS only 5.2 KB (csr/scatter scratch) -> occupancy VGPR-limited.
__global__ __launch_bounds__(256) void mega_kernel(GParams p){
    namespace cg = cooperative_groups;
    cg::grid_group grid = cg::this_grid();
    __shared__ int smi[1280];                 // scratch for scatter/csr phases
    __shared__ int s_is64, s_isf, s_vote;
    const int t   = threadIdx.x;
    const int bid = blockIdx.x;
    const int nb  = gridDim.x;

    // -------- block-local dtype detection (L2-hot after first block) --------
    if (t == 0) s_vote = 0;
    __syncthreads();
    if (t < 64){
        unsigned long long m = __ballot(((const unsigned*)p.ei)[2*t + 1] != 0u);
        if (t == 0) s_is64 = (m == 0ull) ? 1 : 0;
    }
    {
        unsigned lo = p.xw[t] & 0xffffu;
        unsigned e  = (lo >> 7) & 0xffu;
        int pl = ((lo & 0x7fffu) == 0u || (e >= 100u && e <= 140u)) ? 1 : 0;
        atomicAdd(&s_vote, pl);
    }
    __syncthreads();
    if (t == 0) s_isf = (s_vote < 128) ? 1 : 0;
    __syncthreads();
    const int is64 = s_is64, isf = s_isf;

    // ================= phase 0: gcur zero + weight prep =================
    if (bid == 0 && t < NBK) p.gcur[t] = 0;
    {
        const int tid = bid * 256 + t;
        const int NT  = nb * 256;
        // wts tail (attn vecs + biases), indices 20480..20992
        for (int i = tid; i < 513; i += NT){
            int gi = 20480 + i;
            const void* src; int off;
            if      (gi < 20608){ src = p.a1s; off = gi - 20480; }
            else if (gi < 20736){ src = p.a1d; off = gi - 20608; }
            else if (gi < 20864){ src = p.b1;  off = gi - 20736; }
            else if (gi < 20896){ src = p.a2s; off = gi - 20864; }
            else if (gi < 20928){ src = p.a2d; off = gi - 20896; }
            else if (gi < 20960){ src = p.b2;  off = gi - 20928; }
            else if (gi < 20992){ src = p.Wh;  off = gi - 20960; }
            else                { src = p.bh;  off = 0; }
            p.wts[gi] = ldraw(src, off, isf);
        }
        // W1^T bf16 (rows 0-127 of w1x)
        for (int i = tid; i < 16384; i += NT){
            int c = i >> 7, k = i & 127;
            p.w1x[i] = f2bf(ldraw(p.W1, k*128 + c, isf));
        }
        // fused logit vectors layer 1: rows 128+h/136+h = va1s hi/lo; 144+h/152+h = va1d hi/lo
        for (int i = tid; i < 1024; i += NT){          // i = h*128 + k
            int h = i >> 7, k = i & 127;
            float ss = 0.f, dd = 0.f;
#pragma unroll
            for (int j = 0; j < 16; j++){
                float hv = ldraw(p.W1, k*128 + h*16 + j, isf);
                ss += hv * ldraw(p.a1s, h*16 + j, isf);
                dd += hv * ldraw(p.a1d, h*16 + j, isf);
            }
            unsigned short sh = f2bf(ss), dh = f2bf(dd);
            p.w1x[(128+h)*128 + k] = sh;
            p.w1x[(136+h)*128 + k] = f2bf(ss - bfs2f(sh));
            p.w1x[(144+h)*128 + k] = dh;
            p.w1x[(152+h)*128 + k] = f2bf(dd - bfs2f(dh));
        }
        // W2^T bf16 (rows 0-31 of w2x) + zero pad rows 36-47
        for (int i = tid; i < 4096; i += NT){
            int c = i >> 7, k = i & 127;
            p.w2x[i] = f2bf(ldraw(p.W2, k*32 + c, isf));
        }
        for (int i = tid; i < 12*128; i += NT) p.w2x[36*128 + i] = 0;
        // fused logit vectors layer 2: rows 32/33 va2s hi/lo, 34/35 va2d hi/lo
        for (int k = tid; k < 128; k += NT){
            float ss = 0.f, dd = 0.f;
#pragma unroll
            for (int j = 0; j < 32; j++){
                float hv = ldraw(p.W2, k*32 + j, isf);
                ss += hv * ldraw(p.a2s, j, isf);
                dd += hv * ldraw(p.a2d, j, isf);
            }
            unsigned short sh = f2bf(ss), dh = f2bf(dd);
            p.w2x[32*128 + k] = sh;
            p.w2x[33*128 + k] = f2bf(ss - bfs2f(sh));
            p.w2x[34*128 + k] = dh;
            p.w2x[35*128 + k] = f2bf(dd - bfs2f(dh));
        }
    }
    grid.sync();

    // ================= phase 1: bucket scatter =================
    {
        int* cnt  = smi;                 // NBK
        int* base = smi + 256;           // NBK
        int* lcnt = smi + 512;           // NBK
        for (int tile = bid; tile < p.nsb; tile += nb){
            const int e0 = tile * 4096;
            const int nE = min(4096, p.Et - e0);
            for (int i = t; i < NBK; i += 256){ cnt[i] = 0; lcnt[i] = 0; }
            __syncthreads();
            int2 sd[16];
#pragma unroll
            for (int k = 0; k < 16; k++){
                int j = t + k * 256;
                if (j < nE){
                    int e = e0 + j, s, d;
                    if (e >= p.Ee){ s = e - p.Ee; d = s; }
                    else if (is64){
                        const long long* q = (const long long*)p.ei;
                        s = (int)q[e]; d = (int)q[(size_t)p.Ee + e];
                    } else {
                        const int* q = (const int*)p.ei;
                        s = q[e]; d = q[(size_t)p.Ee + e];
                    }
                    sd[k] = make_int2(s, d);
                    atomicAdd(&cnt[d >> BWSH], 1);
                } else sd[k].y = -1;
            }
            __syncthreads();
            for (int b = t; b < NBK; b += 256)
                base[b] = cnt[b] ? (b * BCAP + atomicAdd(&p.gcur[b], cnt[b])) : 0;
            __syncthreads();
#pragma unroll
            for (int k = 0; k < 16; k++){
                if (sd[k].y >= 0){
                    int b = sd[k].y >> BWSH;
                    int r = atomicAdd(&lcnt[b], 1);
                    p.pairs[(size_t)base[b] + r] =
                        ((unsigned)sd[k].x << BWSH) | (unsigned)(sd[k].y & 511);
                }
            }
            __syncthreads();                 // protect smi before next tile
        }
    }
    grid.sync();

    // ================= phase 2: csr_build ∥ GEMM1+attn1 =================
    {
        const int tot = NBK + p.ngemm;
        for (int i = bid; i < tot; i += nb){
            if (i < NBK){
                // ---------------- csr_build bucket i ----------------
                int* ssz   = smi;            // 256
                int* sscan = smi + 256;      // 256
                int* cnt   = smi + 512;      // 512
                int* sh    = smi + 1024;     // 256
                const int b = i;
                int v = (t < NBK) ? p.gcur[t] : 0;
                ssz[t] = v; sscan[t] = v;
                __syncthreads();
                for (int off = 1; off < 256; off <<= 1){
                    int x2 = (t >= off) ? sscan[t - off] : 0;
                    __syncthreads();
                    sscan[t] += x2;
                    __syncthreads();
                }
                const int sz = ssz[b];
                const int eb = (b == 0) ? 0 : sscan[b - 1];
                if (b == 0 && t == 0) p.rowptr[p.Nn] = sscan[NBK - 1];
                const unsigned* pp = p.pairs + (size_t)b * BCAP;
                cnt[t] = 0; cnt[t + 256] = 0;
                __syncthreads();
                for (int j = t; j < sz; j += 256) atomicAdd(&cnt[pp[j] & 511u], 1);
                __syncthreads();
                int l0 = 2*t, l1 = 2*t + 1;
                int s0 = cnt[l0], s1 = cnt[l1], ts = s0 + s1;
                sh[t] = ts; __syncthreads();
                for (int off = 1; off < 256; off <<= 1){
                    int x2 = (t >= off) ? sh[t - off] : 0;
                    __syncthreads();
                    sh[t] += x2;
                    __syncthreads();
                }
                int excl = sh[t] - ts;
                __syncthreads();
                cnt[l0] = eb + excl;
                cnt[l1] = eb + excl + s0;
                int n0 = (b << BWSH) + l0, n1 = (b << BWSH) + l1;
                if (n0 < p.Nn) p.rowptr[n0] = cnt[l0];
                if (n1 < p.Nn) p.rowptr[n1] = cnt[l1];
                __syncthreads();
                for (int j = t; j < sz; j += 256){
                    unsigned sd = pp[j];
                    int pos = atomicAdd(&cnt[sd & 511u], 1);
                    p.csrs[pos] = (int)(sd >> BWSH);
                }
                __syncthreads();
            } else {
                // ---------------- gemm1 tile (LDS-free) ----------------
                const int row0 = (i - NBK) * 64;
                const int w    = t >> 6;
                const int lane = t & 63;
                const int l15  = lane & 15;
                const int quad = lane >> 4;
                const int r0   = row0 + w * 16 + l15;    // A row for this lane
                const bool arow = r0 < p.Nn;

                f32x4 acc[8] = {};
                f32x4 accS = {}, accD = {};
#pragma unroll
                for (int ks = 0; ks < 4; ks++){
                    bf16x8 af;
                    if (arow){
                        if (isf){
                            const float* xp = (const float*)p.xw + (size_t)r0 * 128 + quad * 8 + ks * 32;
                            float4 v0 = *(const float4*)xp;
                            float4 v1 = *(const float4*)(xp + 4);
                            union { bf16x8 v; unsigned short s[8]; } u;
                            u.s[0]=f2bf(v0.x); u.s[1]=f2bf(v0.y); u.s[2]=f2bf(v0.z); u.s[3]=f2bf(v0.w);
                            u.s[4]=f2bf(v1.x); u.s[5]=f2bf(v1.y); u.s[6]=f2bf(v1.z); u.s[7]=f2bf(v1.w);
                            af = u.v;
                        } else {
                            af = *(const bf16x8*)((const unsigned short*)p.xw + (size_t)r0 * 128 + quad * 8 + ks * 32);
                        }
                    } else {
                        union { bf16x8 v; unsigned short s[8]; } u;
#pragma unroll
                        for (int j = 0; j < 8; j++) u.s[j] = 0;
                        af = u.v;
                    }
#pragma unroll
                    for (int tt = 0; tt < 8; tt++){
                        bf16x8 bfr = *(const bf16x8*)(p.w1x + (tt*16 + l15)*128 + quad*8 + ks*32);
                        acc[tt] = __builtin_amdgcn_mfma_f32_16x16x32_bf16(af, bfr, acc[tt], 0, 0, 0);
                    }
                    bf16x8 bS = *(const bf16x8*)(p.w1x + (128 + l15)*128 + quad*8 + ks*32);
                    bf16x8 bD = *(const bf16x8*)(p.w1x + (144 + l15)*128 + quad*8 + ks*32);
                    accS = __builtin_amdgcn_mfma_f32_16x16x32_bf16(af, bS, accS, 0, 0, 0);
                    accD = __builtin_amdgcn_mfma_f32_16x16x32_bf16(af, bD, accD, 0, 0, 0);
                }
#pragma unroll
                for (int tt = 0; tt < 8; tt++){
                    int col = tt * 16 + l15;
#pragma unroll
                    for (int r = 0; r < 4; r++){
                        int row = row0 + w * 16 + quad * 4 + r;
                        if (row < p.Nn) p.h1b[(size_t)row * 128 + col] = f2bf(acc[tt][r]);
                    }
                }
#pragma unroll
                for (int r = 0; r < 4; r++){
                    float vs = accS[r] + __shfl_xor(accS[r], 8);   // hi + lo
                    float vd = accD[r] + __shfl_xor(accD[r], 8);
                    int row = row0 + w * 16 + quad * 4 + r;
                    if (l15 < 8 && row < p.Nn){
                        p.as1[(size_t)row * 8 + l15] = vs;
                        p.ad1[(size_t)row * 8 + l15] = vd;
                    }
                }
            }
        }
    }
    grid.sync();

    // ================= phase 3: gather L1 (+bias+ELU) =================
    {
        const float* b1v = p.wts + 20736;
        for (int i = bid; i < p.nq; i += nb){
            const int wv   = t >> 6;
            const int lane = t & 63;
            const int wid0 = i * 4 + wv;
            const bool active = wid0 < p.Nn;
            const int wid  = active ? wid0 : 0;
            const int q    = lane >> 4;
            const int l15  = lane & 15;
            const int h    = l15 >> 1;
            const int start = active ? p.rowptr[wid] : 0;
            const int end   = active ? p.rowptr[wid + 1] : 0;
            const float adv = p.ad1[(size_t)wid * 8 + h];
            float den = 0.f;
            float num[8] = {0.f,0.f,0.f,0.f,0.f,0.f,0.f,0.f};
            for (int j = start + q; j < end; j += 4){
                int src = p.csrs[j];
                float u = lrelu(p.as1[(size_t)src * 8 + h] + adv);
                float w = __expf(u);
                uint4 hv = *(const uint4*)((const unsigned*)p.h1b + (size_t)src * 64 + (l15 << 2));
                den += w;
                num[0] += w * lo_bf(hv.x); num[1] += w * hi_bf(hv.x);
                num[2] += w * lo_bf(hv.y); num[3] += w * hi_bf(hv.y);
                num[4] += w * lo_bf(hv.z); num[5] += w * hi_bf(hv.z);
                num[6] += w * lo_bf(hv.w); num[7] += w * hi_bf(hv.w);
            }
            den += __shfl_xor(den, 16); den += __shfl_xor(den, 32);
#pragma unroll
            for (int k = 0; k < 8; k++){
                num[k] += __shfl_xor(num[k], 16);
                num[k] += __shfl_xor(num[k], 32);
            }
            if (active && lane < 16){
                const int ch0 = l15 * 8;
                float inv = 1.f / (den + 1e-16f);
                uint4 o;
                unsigned* op = (unsigned*)&o;
#pragma unroll
                for (int k = 0; k < 4; k++){
                    float r0 = num[2*k]   * inv + b1v[ch0 + 2*k];
                    float r1 = num[2*k+1] * inv + b1v[ch0 + 2*k + 1];
                    r0 = r0 > 0.f ? r0 : __expf(r0) - 1.f;
                    r1 = r1 > 0.f ? r1 : __expf(r1) - 1.f;
                    op[k] = (unsigned)f2bf(r0) | ((unsigned)f2bf(r1) << 16);
                }
                *(uint4*)(p.out1u + (size_t)wid * 64 + (l15 << 2)) = o;
            }
        }
    }
    grid.sync();

    // ================= phase 4: GEMM2 + attn2 (LDS-free) =================
    {
        for (int i = bid; i < p.ngemm; i += nb){
            const int row0 = i * 64;
            const int w    = t >> 6;
            const int lane = t & 63;
            const int l15  = lane & 15;
            const int quad = lane >> 4;
            const int r0   = row0 + w * 16 + l15;
            const bool arow = r0 < p.Nn;

            f32x4 acc[2] = {};
            f32x4 accE = {};
#pragma unroll
            for (int ks = 0; ks < 4; ks++){
                bf16x8 af;
                if (arow){
                    af = *(const bf16x8*)((const unsigned short*)p.out1u + (size_t)r0 * 128 + quad * 8 + ks * 32);
                } else {
                    union { bf16x8 v; unsigned short s[8]; } u;
#pragma unroll
                    for (int j = 0; j < 8; j++) u.s[j] = 0;
                    af = u.v;
                }
#pragma unroll
                for (int tt = 0; tt < 2; tt++){
                    bf16x8 bfr = *(const bf16x8*)(p.w2x + (tt*16 + l15)*128 + quad*8 + ks*32);
                    acc[tt] = __builtin_amdgcn_mfma_f32_16x16x32_bf16(af, bfr, acc[tt], 0, 0, 0);
                }
                bf16x8 bE = *(const bf16x8*)(p.w2x + (32 + l15)*128 + quad*8 + ks*32);
                accE = __builtin_amdgcn_mfma_f32_16x16x32_bf16(af, bE, accE, 0, 0, 0);
            }
#pragma unroll
            for (int r = 0; r < 4; r++){
                int row = row0 + w * 16 + quad * 4 + r;
                if (row < p.Nn){
#pragma unroll
                    for (int tt = 0; tt < 2; tt++){
                        int col = tt * 16 + l15;
                        p.h2b[(size_t)row * 32 + col] = f2bf(acc[tt][r]);
                    }
                }
                float vE = accE[r] + __shfl_xor(accE[r], 1);  // hi + lo
                if (row < p.Nn){
                    if (l15 == 0) p.as2[row] = vE;            // cols 32+33
                    if (l15 == 2) p.ad2[row] = vE;            // cols 34+35
                }
            }
        }
    }
    grid.sync();

    // ================= phase 5: gather L2 + ordinal head =================
    {
        const float* b2v = p.wts + 20928;
        const float* Whv = p.wts + 20960;
        const float* bhv = p.wts + 20992;
        for (int i = bid; i < p.nq; i += nb){
            const int wv   = t >> 6;
            const int lane = t & 63;
            const int wid0 = i * 4 + wv;
            const bool active = wid0 < p.Nn;
            const int wid  = active ? wid0 : 0;
            const int q    = lane >> 4;
            const int i2   = lane & 15;
            const int ch0  = i2 * 2;
            const int start = active ? p.rowptr[wid] : 0;
            const int end   = active ? p.rowptr[wid + 1] : 0;
            const float adv = p.ad2[wid];
            float den = 0.f, num0 = 0.f, num1 = 0.f;
            for (int j = start + q; j < end; j += 4){
                int src = p.csrs[j];
                float u = lrelu(p.as2[src] + adv);
                float w = __expf(u);
                unsigned hv = ((const unsigned*)p.h2b)[(size_t)src * 16 + i2];
                den += w;
                num0 += w * lo_bf(hv);
                num1 += w * hi_bf(hv);
            }
            den  += __shfl_xor(den, 16);  den  += __shfl_xor(den, 32);
            num0 += __shfl_xor(num0, 16); num0 += __shfl_xor(num0, 32);
            num1 += __shfl_xor(num1, 16); num1 += __shfl_xor(num1, 32);
            float inv = 1.f / (den + 1e-16f);
            float v0 = num0 * inv + b2v[ch0];
            float v1 = num1 * inv + b2v[ch0 + 1];
            v0 = v0 > 0.f ? v0 : __expf(v0) - 1.f;
            v1 = v1 > 0.f ? v1 : __expf(v1) - 1.f;
            float pr = v0 * Whv[ch0] + v1 * Whv[ch0 + 1];
#pragma unroll
            for (int off = 1; off < 16; off <<= 1) pr += __shfl_xor(pr, off);
            if (active && lane == 0){
                float r = pr + bhv[0];
                if (isf) ((float*)p.out)[wid] = r;
                else     ((__hip_bfloat16*)p.out)[wid] = __float2bfloat16(r);
            }
        }
    }
}

extern "C" void kernel_launch(void* const* d_in, const int* in_sizes, int n_in,
                              void* d_out, int out_size, void* d_ws, size_t ws_size,
                              hipStream_t stream){
    const int Nn = in_sizes[0] / 128;     // 100000
    const int Ee = in_sizes[1] / 2;       // 1600000
    const int Et = Ee + Nn;               // 1700000

    char* ws = (char*)d_ws;
    auto al = [](size_t v){ return (v + 255) & ~(size_t)255; };
    size_t off = 0;
    float*    wts    = (float*)(ws + off);    off = al(off + (size_t)WTS_TOTAL * 4);
    unsigned short* w1x = (unsigned short*)(ws + off); off = al(off + 160 * 128 * 2);
    unsigned short* w2x = (unsigned short*)(ws + off); off = al(off + 48 * 128 * 2);
    int*      gcur   = (int*)(ws + off);      off = al(off + (size_t)NBK * 4);
    int*      rowptr = (int*)(ws + off);      off = al(off + (size_t)(Nn + 1) * 4);
    int*      csrs   = (int*)(ws + off);      off = al(off + (size_t)Et * 4);
    unsigned* pairs  = (unsigned*)(ws + off); off = al(off + (size_t)NBK * BCAP * 4);
    unsigned short* h1b = (unsigned short*)(ws + off); off = al(off + (size_t)Nn * 128 * 2);
    float* as1  = (float*)(ws + off); off = al(off + (size_t)Nn * 8 * 4);
    float* ad1  = (float*)(ws + off); off = al(off + (size_t)Nn * 8 * 4);
    unsigned* out1u = (unsigned*)(ws + off); off = al(off + (size_t)Nn * 128 * 2);
    unsigned short* h2b = (unsigned short*)(ws + off); off = al(off + (size_t)Nn * 32 * 2);
    float* as2  = (float*)(ws + off); off = al(off + (size_t)Nn * 4);
    float* ad2  = (float*)(ws + off); off = al(off + (size_t)Nn * 4);

    GParams P;
    P.ei = d_in[1]; P.xw = (const unsigned*)d_in[0];
    P.W1 = d_in[2]; P.W2 = d_in[6];
    P.a1s = d_in[3]; P.a1d = d_in[4]; P.b1 = d_in[5];
    P.a2s = d_in[7]; P.a2d = d_in[8]; P.b2 = d_in[9];
    P.Wh = d_in[10]; P.bh = d_in[11];
    P.wts = wts; P.w1x = w1x; P.w2x = w2x;
    P.gcur = gcur; P.rowptr = rowptr; P.csrs = csrs; P.pairs = pairs;
    P.h1b = h1b; P.as1 = as1; P.ad1 = ad1;
    P.out1u = out1u; P.h2b = h2b; P.as2 = as2; P.ad2 = ad2;
    P.out = d_out;
    P.Nn = Nn; P.Ee = Ee; P.Et = Et;
    P.nsb = (Et + 4095) / 4096;
    P.ngemm = (Nn + 63) / 64;
    P.nq = (Nn + 3) / 4;

    int maxB = 0;
    hipOccupancyMaxActiveBlocksPerMultiprocessor(&maxB, mega_kernel, 256, 0);
    if (maxB < 1) maxB = 1;
    if (maxB > 8) maxB = 8;                  // 32 waves/CU cap at 256 thr/block
    int grid = maxB * 256;                   // 256 CUs on MI355X (gfx950)

    void* args[] = { &P };
    hipLaunchCooperativeKernel((void*)mega_kernel, dim3(grid), dim3(256),
                               args, 0, stream);
}